// Round 5
// baseline (270.638 us; speedup 1.0000x reference)
//
#include <hip/hip_runtime.h>
#include <stdint.h>

typedef __attribute__((ext_vector_type(8)))  short s16x8;   // 8 x bf16
typedef __attribute__((ext_vector_type(16))) float f32x16;  // 32x32 MFMA acc

union CvtI4 { int4 i; s16x8 s; };
union Cvt4U { unsigned u[4]; s16x8 s; };

__device__ __forceinline__ unsigned f2bf(float f) {
    union { float f; unsigned u; } v; v.f = f;
    return (v.u + 0x7fffu + ((v.u >> 16) & 1u)) >> 16;     // RNE
}

// ---------------------------------------------------------------------------
// k_prep: grid 1024 = (b, n0-chunk, half). LDS-transpose x tile ->
//   xT[b][n][c] = bf16(x * sqrt(log2e/8)), vbf[b][c][n] = bf16(relu(bn1(w1.x)))
// ---------------------------------------------------------------------------
__global__ __launch_bounds__(256) void k_prep(
    const float* __restrict__ x, const float* __restrict__ w1,
    const float* __restrict__ g1, const float* __restrict__ b1,
    const float* __restrict__ m1, const float* __restrict__ v1,
    unsigned short* __restrict__ xT, unsigned short* __restrict__ vbf)
{
    __shared__ float X[64 * 65];   // [c][n] pad+1
    const int b    = blockIdx.x >> 7;
    const int n0   = ((blockIdx.x >> 1) & 63) << 6;
    const int half = blockIdx.x & 1;
    const int tid  = threadIdx.x;
    const float QS = 0.42466090014400953f;   // sqrt(log2(e)/8)

    {
        const int r = tid >> 6, nn = tid & 63;
        const float* xb = x + (size_t)b * 262144 + n0 + nn;
#pragma unroll
        for (int cc = 0; cc < 16; ++cc) {
            int c = cc * 4 + r;
            X[c * 65 + nn] = xb[(size_t)c * 4096];
        }
    }
    __syncthreads();

    {   // xT: 32 n rows, 8 threads per 128B row
        const int n8 = tid >> 3, c8 = tid & 7;
        const int n = (half << 5) + n8;
        unsigned u[4];
#pragma unroll
        for (int j = 0; j < 4; ++j) {
            unsigned lo = f2bf(X[(c8 * 8 + 2 * j) * 65 + n] * QS);
            unsigned hi = f2bf(X[(c8 * 8 + 2 * j + 1) * 65 + n] * QS);
            u[j] = lo | (hi << 16);
        }
        uint4 pk; pk.x = u[0]; pk.y = u[1]; pk.z = u[2]; pk.w = u[3];
        *(uint4*)(xT + (((size_t)((b << 12) + n0 + n)) << 6) + (c8 << 3)) = pk;
    }

    {   // V = relu(bn1(conv1x1)): 32 output channels for this half
        const int n = tid & 63, og = tid >> 6;
        float rX[64];
#pragma unroll
        for (int c = 0; c < 64; ++c) rX[c] = X[c * 65 + n];
        unsigned short* vb = vbf + (((size_t)(b << 6)) << 12) + n0 + n;
#pragma unroll 2
        for (int oo = 0; oo < 8; ++oo) {
            int o = (half << 5) + og * 8 + oo;
            float inv = g1[o] * rsqrtf(v1[o] + 1e-5f);
            float sh  = b1[o] - m1[o] * inv;
            float acc = 0.f;
#pragma unroll
            for (int c = 0; c < 64; ++c) acc = fmaf(w1[o * 64 + c], rX[c], acc);
            vb[(size_t)o << 12] = (unsigned short)f2bf(fmaxf(fmaf(acc, inv, sh), 0.f));
        }
    }
}

// ---------------------------------------------------------------------------
// k_attn v5: ZERO-LDS, ZERO-BARRIER flash attention.
// Per wave: 32 queries, m-tiles of 32. 32x32x16 MFMA throughout.
//   S^T = K.Q^T : A=K rows (global 16B), B=Q rows (held).
//                 lane holds n=lane&31 fixed, m=(r&3)+8*(r>>2)+4*half.
//   P stays IN REGISTERS: the PV B-operand P[m][n=lane&31] needs exactly the
//   S lane-layout modulo a half<->half swap of reg-pairs -> 2 shfl_xor(32)
//   + cndmask per k-step. O^T = V.P : A=V rows (global 16B).
//   Normalization free: denom lives in the same n=lane&31 slot as O's cols.
// grid = 256*nsplit (4 waves/block); b = XCD for L2 locality; zero tail.
// ---------------------------------------------------------------------------
__global__ __launch_bounds__(256, 4) void k_attn(
    const unsigned short* __restrict__ xT, const unsigned short* __restrict__ vbf,
    float* __restrict__ outO, float* __restrict__ outL,
    int tilesPer, int normalize)
{
    const int b    = blockIdx.x & 7;          // batch == XCD slice
    const int slot = blockIdx.x >> 3;
    const int ms   = slot >> 5;
    const int qgrp = slot & 31;
    const int tid  = threadIdx.x;
    const int w = tid >> 6, lane = tid & 63;
    const int l31 = lane & 31, h = lane >> 5;

    outO += (size_t)ms * 2097152u;   // 8*4096*64 per split
    outL += (size_t)ms * 32768u;

    const int qbase = (qgrp << 7) + (w << 5);

    // Q B-fragments (held): B[k = kk*16 + 8h + j][n = l31]
    s16x8 Bq[4];
    {
        const unsigned short* qr = xT + (((size_t)((b << 12) + qbase + l31)) << 6) + (h << 3);
#pragma unroll
        for (int kk = 0; kk < 4; ++kk) {
            CvtI4 c; c.i = *(const int4*)(qr + (kk << 4));
            Bq[kk] = c.s;
        }
    }

    f32x16 O0 = {0.f,0.f,0.f,0.f,0.f,0.f,0.f,0.f,0.f,0.f,0.f,0.f,0.f,0.f,0.f,0.f};
    f32x16 O1 = O0;
    float rs = 0.f;
    const int mt0 = ms * tilesPer;

    for (int mt = 0; mt < tilesPer; ++mt) {
        const int m0 = (mt0 + mt) << 5;

        // K A-fragments: A[m = m0+l31][k = kk*16 + 8h + j]
        const unsigned short* kr = xT + (((size_t)((b << 12) + m0 + l31)) << 6) + (h << 3);
        s16x8 Ak0, Ak1, Ak2, Ak3;
        { CvtI4 c; c.i = *(const int4*)(kr);      Ak0 = c.s; }
        { CvtI4 c; c.i = *(const int4*)(kr + 16); Ak1 = c.s; }
        { CvtI4 c; c.i = *(const int4*)(kr + 32); Ak2 = c.s; }
        { CvtI4 c; c.i = *(const int4*)(kr + 48); Ak3 = c.s; }

        f32x16 S = {0.f,0.f,0.f,0.f,0.f,0.f,0.f,0.f,0.f,0.f,0.f,0.f,0.f,0.f,0.f,0.f};
        S = __builtin_amdgcn_mfma_f32_32x32x16_bf16(Ak0, Bq[0], S, 0, 0, 0);
        S = __builtin_amdgcn_mfma_f32_32x32x16_bf16(Ak1, Bq[1], S, 0, 0, 0);
        S = __builtin_amdgcn_mfma_f32_32x32x16_bf16(Ak2, Bq[2], S, 0, 0, 0);
        S = __builtin_amdgcn_mfma_f32_32x32x16_bf16(Ak3, Bq[3], S, 0, 0, 0);

        // P = exp2(S), packed in-register. P2[2q+s] = bf16x2 of m = 8q+4h+2s+{0,1}
        unsigned P2[8];
#pragma unroll
        for (int q = 0; q < 4; ++q) {
            float p0 = __builtin_amdgcn_exp2f(S[4*q+0]);
            float p1 = __builtin_amdgcn_exp2f(S[4*q+1]);
            float p2 = __builtin_amdgcn_exp2f(S[4*q+2]);
            float p3 = __builtin_amdgcn_exp2f(S[4*q+3]);
            rs += (p0 + p1) + (p2 + p3);
            union { float f; unsigned u; } a0, a1, a2, a3;
            a0.f = p0; a1.f = p1; a2.f = p2; a3.f = p3;
            P2[2*q]   = __builtin_amdgcn_perm(a1.u + 0x8000u, a0.u + 0x8000u, 0x07060302u);
            P2[2*q+1] = __builtin_amdgcn_perm(a3.u + 0x8000u, a2.u + 0x8000u, 0x07060302u);
        }

        // PV: O^T[d][n] += V.P  — B-frag P[m = ks*16+8h+j][n=l31] built from
        // own pair P2[4ks+2h..+1] and partner-half pair via shfl_xor(32).
#pragma unroll
        for (int ks = 0; ks < 2; ++ks) {
            unsigned s0 = P2[4*ks + 2 - 2*h];
            unsigned s1 = P2[4*ks + 3 - 2*h];
            unsigned r0 = __shfl_xor((int)s0, 32);
            unsigned r1 = __shfl_xor((int)s1, 32);
            unsigned o0 = P2[4*ks + 2*h];
            unsigned o1 = P2[4*ks + 2*h + 1];
            Cvt4U bp;
            bp.u[0] = h ? r0 : o0;
            bp.u[1] = h ? r1 : o1;
            bp.u[2] = h ? o0 : r0;
            bp.u[3] = h ? o1 : r1;
            const unsigned short* vr = vbf + (((size_t)((b << 6) + l31)) << 12)
                                     + m0 + (ks << 4) + (h << 3);
            { CvtI4 c; c.i = *(const int4*)(vr);
              O0 = __builtin_amdgcn_mfma_f32_32x32x16_bf16(c.s, bp.s, O0, 0, 0, 0); }
            { CvtI4 c; c.i = *(const int4*)(vr + (32u << 12));
              O1 = __builtin_amdgcn_mfma_f32_32x32x16_bf16(c.s, bp.s, O1, 0, 0, 0); }
        }
    }

    // denom for n = qbase + l31 (both halves end with the full sum)
    rs += __shfl_xor(rs, 32);

    const int nb = (b << 12) + qbase + l31;     // output row index (n)
    float* orow = outO + ((size_t)nb << 6);
    if (normalize) {
        float inv = 1.f / rs;
#pragma unroll
        for (int r = 0; r < 16; ++r) {
            int d = (r & 3) + ((r >> 2) << 3) + (h << 2);
            orow[d]      = O0[r] * inv;
            orow[32 + d] = O1[r] * inv;
        }
    } else {
#pragma unroll
        for (int r = 0; r < 16; ++r) {
            int d = (r & 3) + ((r >> 2) << 3) + (h << 2);
            orow[d]      = O0[r];
            orow[32 + d] = O1[r];
        }
        if (h == 0) outL[nb] = rs;
    }
}

// ---------------------------------------------------------------------------
// k_post: stage 3-row window (combining nsplit partials) into LDS ->
// dwconv3x3 + BN2 + ReLU -> LDS -> pointwise(w3) + BN3 + residual.
// grid 512 = (b, h), 256 thr.
// ---------------------------------------------------------------------------
__global__ __launch_bounds__(256) void k_post(
    const float* __restrict__ Obase, const float* __restrict__ Lbase,
    const float* __restrict__ x,
    const float* __restrict__ w2,
    const float* __restrict__ g2, const float* __restrict__ b2,
    const float* __restrict__ m2, const float* __restrict__ v2,
    const float* __restrict__ w3,
    const float* __restrict__ g3, const float* __restrict__ b3,
    const float* __restrict__ m3, const float* __restrict__ v3,
    float* __restrict__ out, int nsplit, int normalized)
{
    __shared__ float W[3][64 * 66];
    __shared__ float T2[64 * 66];

    const int b = blockIdx.x >> 6;
    const int h = blockIdx.x & 63;
    const int tid = threadIdx.x;

#pragma unroll
    for (int r = 0; r < 3; ++r) {
        int hh = h + r - 1;
        if (hh >= 0 && hh <= 63) {
#pragma unroll
            for (int i = 0; i < 4; ++i) {
                int lin = (i << 8) + tid;
                int w = lin >> 4, cg = lin & 15;
                size_t npos = (size_t)((b << 12) + (hh << 6) + w);
                const float* p0 = Obase + (npos << 6) + (cg << 2);
                float4 a = *(const float4*)p0;
                float sl = normalized ? 0.f : Lbase[npos];
                for (int s = 1; s < nsplit; ++s) {
                    const float4 a2 = *(const float4*)(p0 + (size_t)s * 2097152);
                    a.x += a2.x; a.y += a2.y; a.z += a2.z; a.w += a2.w;
                    sl += Lbase[npos + (size_t)s * 32768];
                }
                float invd = normalized ? 1.f : 1.f / sl;
                a.x *= invd; a.y *= invd; a.z *= invd; a.w *= invd;
                *(float4*)&W[r][w * 66 + (cg << 2)] = a;
            }
        } else {
            float4 z = {0.f, 0.f, 0.f, 0.f};
#pragma unroll
            for (int i = 0; i < 4; ++i) {
                int lin = (i << 8) + tid;
                *(float4*)&W[r][(lin >> 4) * 66 + ((lin & 15) << 2)] = z;
            }
        }
    }
    __syncthreads();

    const int w = tid & 63, cq = tid >> 6;
    float t16[16];
#pragma unroll
    for (int i = 0; i < 16; ++i) t16[i] = 0.f;

#pragma unroll
    for (int ky = 0; ky < 3; ++ky) {
#pragma unroll
        for (int kx = 0; kx < 3; ++kx) {
            int ww = w + kx - 1;
            if (ww < 0 || ww > 63) continue;
            const int k = ky * 3 + kx;
            const float* Wr = &W[ky][ww * 66 + (cq << 4)];
#pragma unroll
            for (int i = 0; i < 4; ++i) {
                float4 a = *(const float4*)(Wr + (i << 2));
                int c = (cq << 4) + (i << 2);
                t16[i * 4 + 0] = fmaf(w2[(c + 0) * 9 + k], a.x, t16[i * 4 + 0]);
                t16[i * 4 + 1] = fmaf(w2[(c + 1) * 9 + k], a.y, t16[i * 4 + 1]);
                t16[i * 4 + 2] = fmaf(w2[(c + 2) * 9 + k], a.z, t16[i * 4 + 2]);
                t16[i * 4 + 3] = fmaf(w2[(c + 3) * 9 + k], a.w, t16[i * 4 + 3]);
            }
        }
    }
#pragma unroll
    for (int i = 0; i < 16; ++i) {
        int c = (cq << 4) + i;
        float inv = g2[c] * rsqrtf(v2[c] + 1e-5f);
        float sh  = b2[c] - m2[c] * inv;
        T2[w * 66 + c] = fmaxf(fmaf(t16[i], inv, sh), 0.f);
    }
    __syncthreads();

    float rT[64];
#pragma unroll
    for (int c4 = 0; c4 < 16; ++c4)
        *(float4*)&rT[c4 << 2] = *(const float4*)&T2[w * 66 + (c4 << 2)];

    const int hw = (h << 6) + w;
#pragma unroll 2
    for (int oo = 0; oo < 16; ++oo) {
        int o = (cq << 4) + oo;
        float inv = g3[o] * rsqrtf(v3[o] + 1e-5f);
        float sh  = b3[o] - m3[o] * inv;
        float acc = 0.f;
#pragma unroll
        for (int c = 0; c < 64; ++c) acc = fmaf(w3[o * 64 + c], rT[c], acc);
        size_t idx = (((size_t)((b << 6) + o)) << 12) + hw;
        out[idx] = fmaf(acc, inv, sh) + x[idx];
    }
}

// ---------------------------------------------------------------------------
extern "C" void kernel_launch(void* const* d_in, const int* in_sizes, int n_in,
                              void* d_out, int out_size, void* d_ws, size_t ws_size,
                              hipStream_t stream)
{
    const float* x  = (const float*)d_in[0];
    const float* w1 = (const float*)d_in[1];
    const float* g1 = (const float*)d_in[2];
    const float* b1 = (const float*)d_in[3];
    const float* m1 = (const float*)d_in[4];
    const float* v1 = (const float*)d_in[5];
    const float* w2 = (const float*)d_in[6];
    const float* g2 = (const float*)d_in[7];
    const float* b2 = (const float*)d_in[8];
    const float* m2 = (const float*)d_in[9];
    const float* v2 = (const float*)d_in[10];
    const float* w3 = (const float*)d_in[11];
    const float* g3 = (const float*)d_in[12];
    const float* b3 = (const float*)d_in[13];
    const float* m3 = (const float*)d_in[14];
    const float* v3 = (const float*)d_in[15];
    float* out = (float*)d_out;

    // ws: xT 4MB | vbf 4MB | O_s nsplit*8MB | L_s nsplit*128KB
    unsigned short* xT  = (unsigned short*)d_ws;
    unsigned short* vbf = xT + (size_t)8 * 4096 * 64;
    float* Obase = (float*)((char*)d_ws + (8u << 20));

    const size_t need4 = (8u << 20) + 4u * ((8u << 20) + (128u << 10));
    const size_t need2 = (8u << 20) + 2u * ((8u << 20) + (128u << 10));
    const int nsplit = (ws_size >= need4) ? 4 : (ws_size >= need2 ? 2 : 1);
    float* Lbase = Obase + (size_t)nsplit * 2097152;

    k_prep<<<1024, 256, 0, stream>>>(x, w1, g1, b1, m1, v1, xT, vbf);
    k_attn<<<256 * nsplit, 256, 0, stream>>>(xT, vbf, Obase, Lbase,
                                             128 / nsplit, nsplit == 1);
    k_post<<<512, 256, 0, stream>>>(Obase, Lbase, x, w2, g2, b2, m2, v2,
                                    w3, g3, b3, m3, v3, out, nsplit, nsplit == 1);
}

// Round 7
// 198.300 us; speedup vs baseline: 1.3648x; 1.3648x over previous
//
#include <hip/hip_runtime.h>
#include <stdint.h>

typedef __attribute__((ext_vector_type(8)))  short s16x8;   // 8 x bf16
typedef __attribute__((ext_vector_type(16))) float f32x16;  // 32x32 MFMA acc

union CvtI4 { int4 i; s16x8 s; };

__device__ __forceinline__ unsigned f2bf(float f) {
    union { float f; unsigned u; } v; v.f = f;
    return (v.u + 0x7fffu + ((v.u >> 16) & 1u)) >> 16;     // RNE
}

// ---------------------------------------------------------------------------
// k_prep: grid 1024 = (b, n0-chunk, half). LDS-transpose x tile ->
//   xT[b][n][c] = bf16(x * sqrt(log2e/8)), vbf[b][c][n] = bf16(relu(bn1(w1.x)))
// ---------------------------------------------------------------------------
__global__ __launch_bounds__(256) void k_prep(
    const float* __restrict__ x, const float* __restrict__ w1,
    const float* __restrict__ g1, const float* __restrict__ b1,
    const float* __restrict__ m1, const float* __restrict__ v1,
    unsigned short* __restrict__ xT, unsigned short* __restrict__ vbf)
{
    __shared__ float X[64 * 65];   // [c][n] pad+1
    const int b    = blockIdx.x >> 7;
    const int n0   = ((blockIdx.x >> 1) & 63) << 6;
    const int half = blockIdx.x & 1;
    const int tid  = threadIdx.x;
    const float QS = 0.42466090014400953f;   // sqrt(log2(e)/8)

    {
        const int r = tid >> 6, nn = tid & 63;
        const float* xb = x + (size_t)b * 262144 + n0 + nn;
#pragma unroll
        for (int cc = 0; cc < 16; ++cc) {
            int c = cc * 4 + r;
            X[c * 65 + nn] = xb[(size_t)c * 4096];
        }
    }
    __syncthreads();

    {   // xT: 32 n rows, 8 threads per 128B row
        const int n8 = tid >> 3, c8 = tid & 7;
        const int n = (half << 5) + n8;
        unsigned u[4];
#pragma unroll
        for (int j = 0; j < 4; ++j) {
            unsigned lo = f2bf(X[(c8 * 8 + 2 * j) * 65 + n] * QS);
            unsigned hi = f2bf(X[(c8 * 8 + 2 * j + 1) * 65 + n] * QS);
            u[j] = lo | (hi << 16);
        }
        uint4 pk; pk.x = u[0]; pk.y = u[1]; pk.z = u[2]; pk.w = u[3];
        *(uint4*)(xT + (((size_t)((b << 12) + n0 + n)) << 6) + (c8 << 3)) = pk;
    }

    {   // V = relu(bn1(conv1x1)): 32 output channels for this half
        const int n = tid & 63, og = tid >> 6;
        float rX[64];
#pragma unroll
        for (int c = 0; c < 64; ++c) rX[c] = X[c * 65 + n];
        unsigned short* vb = vbf + (((size_t)(b << 6)) << 12) + n0 + n;
#pragma unroll 2
        for (int oo = 0; oo < 8; ++oo) {
            int o = (half << 5) + og * 8 + oo;
            float inv = g1[o] * rsqrtf(v1[o] + 1e-5f);
            float sh  = b1[o] - m1[o] * inv;
            float acc = 0.f;
#pragma unroll
            for (int c = 0; c < 64; ++c) acc = fmaf(w1[o * 64 + c], rX[c], acc);
            vb[(size_t)o << 12] = (unsigned short)f2bf(fmaxf(fmaf(acc, inv, sh), 0.f));
        }
    }
}

// ---------------------------------------------------------------------------
// k_attn v7: R4's proven dataflow with m-tile 64 (was 128).
// Block = 4 waves, 64 queries, 32x32x16 MFMA, swizzled LDS, P via LDS.
// QK: wave (s = w&1 -> m-strip, t = w>>1 -> n-half) computes S^T quadrant,
//     exp2 -> P[n][m] in LDS. PV: wave (t_o = w>>1, d32 = w&1) owns O quadrant.
// LDS = K 8KB + V 8KB + P 8KB + ~0.8KB -> 5-6 blocks/CU, grid 1024 no tail.
// ---------------------------------------------------------------------------
__global__ __launch_bounds__(256) void k_attn(
    const unsigned short* __restrict__ xT, const unsigned short* __restrict__ vbf,
    float* __restrict__ outO, float* __restrict__ outL,
    int tilesPer, int nsplit)
{
    __shared__ __align__(16) unsigned short Klds[64 * 64];   // [m][c] swz8
    __shared__ __align__(16) unsigned short Vlds[64 * 64];   // [d][m] swz8
    __shared__ __align__(16) unsigned short Plds[64 * 64];   // [n][m] swz8
    __shared__ float rsLds[4][32];
    __shared__ float denomT[64];

    const int xcd  = blockIdx.x & 7;
    const int slot = blockIdx.x >> 3;
    const int qgrp = slot & 63;
    const int pair = xcd * nsplit + (slot >> 6);
    const int b = pair & 7;
    const int ms = pair >> 3;

    const int tid = threadIdx.x;
    const int w = tid >> 6, lane = tid & 63;
    const int l31 = lane & 31, half = lane >> 5;
    const int qbase = qgrp << 6;

    outO += (size_t)ms * 2097152u;
    outL += (size_t)ms * 32768u;

    const int s = w & 1;      // QK m-strip
    const int t = w >> 1;     // QK n-half

    // Q B-fragments (held): B[k = kk*16 + 8h + j][n = (t<<5) + l31]
    s16x8 Bq[4];
    {
        const unsigned short* qr = xT +
            (((size_t)((b << 12) + qbase + (t << 5) + l31)) << 6) + (half << 3);
#pragma unroll
        for (int kk = 0; kk < 4; ++kk) {
            CvtI4 c; c.i = *(const int4*)(qr + (kk << 4));
            Bq[kk] = c.s;
        }
    }

    f32x16 O = {0.f,0.f,0.f,0.f,0.f,0.f,0.f,0.f,0.f,0.f,0.f,0.f,0.f,0.f,0.f,0.f};
    float rs = 0.f;
    const int mt0 = ms * tilesPer;

    for (int mt = 0; mt < tilesPer; ++mt) {
        const int m0 = (mt0 + mt) << 6;
        __syncthreads();   // prev tile's LDS reads done before restage
#pragma unroll
        for (int it = 0; it < 2; ++it) {
            int lin = (it << 8) + tid;             // 0..511
            {   // K: 64 rows x 128B, chunk swizzle ^ (m&7)
                int km = lin >> 3, c4 = lin & 7;
                int4 d = *(const int4*)(xT + (((size_t)((b << 12) + m0 + km)) << 6) + (c4 << 3));
                *(int4*)(Klds + (km << 6) + ((c4 ^ (km & 7)) << 3)) = d;
            }
            {   // V: 64 rows x 128B (m-chunk), swizzle ^ (d&7)
                int vd = lin >> 3, c8 = lin & 7;
                int4 d = *(const int4*)(vbf + (((size_t)((b << 6) + vd)) << 12) + m0 + (c8 << 3));
                *(int4*)(Vlds + (vd << 6) + ((c8 ^ (vd & 7)) << 3)) = d;
            }
        }
        __syncthreads();

        {   // QK quadrant: A = K rows m = s*32 + l31, B = Bq (n-half t)
            const int km = (s << 5) + l31;
            s16x8 Ak[4];
#pragma unroll
            for (int kk = 0; kk < 4; ++kk) {
                int pos = ((kk << 1) + half) ^ (km & 7);
                Ak[kk] = *(const s16x8*)(Klds + (km << 6) + (pos << 3));
            }
            f32x16 S = {0.f,0.f,0.f,0.f,0.f,0.f,0.f,0.f,0.f,0.f,0.f,0.f,0.f,0.f,0.f,0.f};
            S = __builtin_amdgcn_mfma_f32_32x32x16_bf16(Ak[0], Bq[0], S, 0, 0, 0);
            S = __builtin_amdgcn_mfma_f32_32x32x16_bf16(Ak[1], Bq[1], S, 0, 0, 0);
            S = __builtin_amdgcn_mfma_f32_32x32x16_bf16(Ak[2], Bq[2], S, 0, 0, 0);
            S = __builtin_amdgcn_mfma_f32_32x32x16_bf16(Ak[3], Bq[3], S, 0, 0, 0);

            // P = exp2(S) -> Plds rows n = t*32 + l31, m = 32s + 8q + 4h + 0..3
            const int nrow = (t << 5) + l31;
#pragma unroll
            for (int q = 0; q < 4; ++q) {
                float p0 = __builtin_amdgcn_exp2f(S[4*q+0]);
                float p1 = __builtin_amdgcn_exp2f(S[4*q+1]);
                float p2 = __builtin_amdgcn_exp2f(S[4*q+2]);
                float p3 = __builtin_amdgcn_exp2f(S[4*q+3]);
                rs += (p0 + p1) + (p2 + p3);
                union { float f; unsigned u; } a0, a1, a2, a3;
                a0.f = p0; a1.f = p1; a2.f = p2; a3.f = p3;
                uint2 pk;
                pk.x = ((a0.u + 0x8000u) >> 16) | ((a1.u + 0x8000u) & 0xFFFF0000u);
                pk.y = ((a2.u + 0x8000u) >> 16) | ((a3.u + 0x8000u) & 0xFFFF0000u);
                int c8 = (s << 2) + q;             // m-chunk = (32s + 8q)/8
                *(uint2*)(Plds + (nrow << 6) + ((c8 ^ (nrow & 7)) << 3) + (half << 2)) = pk;
            }
        }
        __syncthreads();

        // PV: wave owns O quadrant (n-half = w>>1, d-half = w&1), full 64 m
        {
            const int nrow = (t << 5) + l31;          // A = P rows (n)
            const int drow = (s << 5) + l31;          // B = V rows (d)
#pragma unroll
            for (int ks = 0; ks < 4; ++ks) {
                int c = (ks << 1) + half;
                const s16x8 Ap = *(const s16x8*)(Plds + (nrow << 6) + ((c ^ (nrow & 7)) << 3));
                const s16x8 Bv = *(const s16x8*)(Vlds + (drow << 6) + ((c ^ (drow & 7)) << 3));
                O = __builtin_amdgcn_mfma_f32_32x32x16_bf16(Ap, Bv, O, 0, 0, 0);
            }
        }
    }

    // denominators: fold halves, then cross-strip (waves 2t and 2t+1) via LDS
    rs += __shfl_xor(rs, 32);
    if (half == 0) rsLds[w][l31] = rs;
    __syncthreads();
    if (tid < 64) {
        int tt = tid >> 5, n = tid & 31;
        denomT[tid] = rsLds[2 * tt][n] + rsLds[2 * tt + 1][n];
    }
    __syncthreads();

    const int nb = (b << 12) + qbase;
    const int n32o = w >> 1, d32 = w & 1;
    if (nsplit == 1) {
#pragma unroll
        for (int r = 0; r < 16; ++r) {
            int nl = (r & 3) + ((r >> 2) << 3) + (half << 2);
            int n = (n32o << 5) + nl;
            float inv = 1.f / denomT[n];
            outO[((size_t)(nb + n) << 6) + (d32 << 5) + l31] = O[r] * inv;
        }
    } else {
#pragma unroll
        for (int r = 0; r < 16; ++r) {
            int nl = (r & 3) + ((r >> 2) << 3) + (half << 2);
            int n = (n32o << 5) + nl;
            outO[((size_t)(nb + n) << 6) + (d32 << 5) + l31] = O[r];
        }
        if (tid < 64) outL[nb + tid] = denomT[tid];
    }
}

// ---------------------------------------------------------------------------
// k_post: stage 3-row window (combining nsplit partials) into LDS ->
// dwconv3x3 + BN2 + ReLU -> LDS -> pointwise(w3) + BN3 + residual.
// grid 512 = (b, h), 256 thr.
// ---------------------------------------------------------------------------
__global__ __launch_bounds__(256) void k_post(
    const float* __restrict__ Obase, const float* __restrict__ Lbase,
    const float* __restrict__ x,
    const float* __restrict__ w2,
    const float* __restrict__ g2, const float* __restrict__ b2,
    const float* __restrict__ m2, const float* __restrict__ v2,
    const float* __restrict__ w3,
    const float* __restrict__ g3, const float* __restrict__ b3,
    const float* __restrict__ m3, const float* __restrict__ v3,
    float* __restrict__ out, int nsplit, int normalized)
{
    __shared__ float W[3][64 * 66];
    __shared__ float T2[64 * 66];

    const int b = blockIdx.x >> 6;
    const int h = blockIdx.x & 63;
    const int tid = threadIdx.x;

#pragma unroll
    for (int r = 0; r < 3; ++r) {
        int hh = h + r - 1;
        if (hh >= 0 && hh <= 63) {
#pragma unroll
            for (int i = 0; i < 4; ++i) {
                int lin = (i << 8) + tid;
                int w = lin >> 4, cg = lin & 15;
                size_t npos = (size_t)((b << 12) + (hh << 6) + w);
                const float* p0 = Obase + (npos << 6) + (cg << 2);
                float4 a = *(const float4*)p0;
                float sl = normalized ? 0.f : Lbase[npos];
                for (int s = 1; s < nsplit; ++s) {
                    const float4 a2 = *(const float4*)(p0 + (size_t)s * 2097152);
                    a.x += a2.x; a.y += a2.y; a.z += a2.z; a.w += a2.w;
                    sl += Lbase[npos + (size_t)s * 32768];
                }
                float invd = normalized ? 1.f : 1.f / sl;
                a.x *= invd; a.y *= invd; a.z *= invd; a.w *= invd;
                *(float4*)&W[r][w * 66 + (cg << 2)] = a;
            }
        } else {
            float4 z = {0.f, 0.f, 0.f, 0.f};
#pragma unroll
            for (int i = 0; i < 4; ++i) {
                int lin = (i << 8) + tid;
                *(float4*)&W[r][(lin >> 4) * 66 + ((lin & 15) << 2)] = z;
            }
        }
    }
    __syncthreads();

    const int w = tid & 63, cq = tid >> 6;
    float t16[16];
#pragma unroll
    for (int i = 0; i < 16; ++i) t16[i] = 0.f;

#pragma unroll
    for (int ky = 0; ky < 3; ++ky) {
#pragma unroll
        for (int kx = 0; kx < 3; ++kx) {
            int ww = w + kx - 1;
            if (ww < 0 || ww > 63) continue;
            const int k = ky * 3 + kx;
            const float* Wr = &W[ky][ww * 66 + (cq << 4)];
#pragma unroll
            for (int i = 0; i < 4; ++i) {
                float4 a = *(const float4*)(Wr + (i << 2));
                int c = (cq << 4) + (i << 2);
                t16[i * 4 + 0] = fmaf(w2[(c + 0) * 9 + k], a.x, t16[i * 4 + 0]);
                t16[i * 4 + 1] = fmaf(w2[(c + 1) * 9 + k], a.y, t16[i * 4 + 1]);
                t16[i * 4 + 2] = fmaf(w2[(c + 2) * 9 + k], a.z, t16[i * 4 + 2]);
                t16[i * 4 + 3] = fmaf(w2[(c + 3) * 9 + k], a.w, t16[i * 4 + 3]);
            }
        }
    }
#pragma unroll
    for (int i = 0; i < 16; ++i) {
        int c = (cq << 4) + i;
        float inv = g2[c] * rsqrtf(v2[c] + 1e-5f);
        float sh  = b2[c] - m2[c] * inv;
        T2[w * 66 + c] = fmaxf(fmaf(t16[i], inv, sh), 0.f);
    }
    __syncthreads();

    float rT[64];
#pragma unroll
    for (int c4 = 0; c4 < 16; ++c4)
        *(float4*)&rT[c4 << 2] = *(const float4*)&T2[w * 66 + (c4 << 2)];

    const int hw = (h << 6) + w;
#pragma unroll 2
    for (int oo = 0; oo < 16; ++oo) {
        int o = (cq << 4) + oo;
        float inv = g3[o] * rsqrtf(v3[o] + 1e-5f);
        float sh  = b3[o] - m3[o] * inv;
        float acc = 0.f;
#pragma unroll
        for (int c = 0; c < 64; ++c) acc = fmaf(w3[o * 64 + c], rT[c], acc);
        size_t idx = (((size_t)((b << 6) + o)) << 12) + hw;
        out[idx] = fmaf(acc, inv, sh) + x[idx];
    }
}

// ---------------------------------------------------------------------------
extern "C" void kernel_launch(void* const* d_in, const int* in_sizes, int n_in,
                              void* d_out, int out_size, void* d_ws, size_t ws_size,
                              hipStream_t stream)
{
    const float* x  = (const float*)d_in[0];
    const float* w1 = (const float*)d_in[1];
    const float* g1 = (const float*)d_in[2];
    const float* b1 = (const float*)d_in[3];
    const float* m1 = (const float*)d_in[4];
    const float* v1 = (const float*)d_in[5];
    const float* w2 = (const float*)d_in[6];
    const float* g2 = (const float*)d_in[7];
    const float* b2 = (const float*)d_in[8];
    const float* m2 = (const float*)d_in[9];
    const float* v2 = (const float*)d_in[10];
    const float* w3 = (const float*)d_in[11];
    const float* g3 = (const float*)d_in[12];
    const float* b3 = (const float*)d_in[13];
    const float* m3 = (const float*)d_in[14];
    const float* v3 = (const float*)d_in[15];
    float* out = (float*)d_out;

    // ws: xT 4MB | vbf 4MB | O_s nsplit*8MB | L_s nsplit*128KB
    unsigned short* xT  = (unsigned short*)d_ws;
    unsigned short* vbf = xT + (size_t)8 * 4096 * 64;
    float* Obase = (float*)((char*)d_ws + (8u << 20));

    const size_t need2 = (8u << 20) + 2u * ((8u << 20) + (128u << 10));
    const int nsplit = (ws_size >= need2) ? 2 : 1;
    float* Lbase = Obase + (size_t)nsplit * 2097152;

    k_prep<<<1024, 256, 0, stream>>>(x, w1, g1, b1, m1, v1, xT, vbf);
    k_attn<<<nsplit * 512, 256, 0, stream>>>(xT, vbf, Obase, Lbase,
                                             64 / nsplit, nsplit);
    k_post<<<512, 256, 0, stream>>>(Obase, Lbase, x, w2, g2, b2, m2, v2,
                                    w3, g3, b3, m3, v3, out, nsplit, nsplit == 1);
}